// Round 1
// baseline (827.731 us; speedup 1.0000x reference)
//
#include <hip/hip_runtime.h>

// LSTMCell fused: out = sigmoid([sigmoid([x|h]@Wih + b_ih) | h] @ Whh + b_hh)
// B=524288, all dims 128/256. fp32 in/out, split-bf16 (hi+lo) MFMA emulation.

typedef __bf16 bf16x8 __attribute__((ext_vector_type(8)));
typedef float floatx4 __attribute__((ext_vector_type(4)));

// Packed weights: [plane][fragslot][8]  plane 0=ih_hi 1=ih_lo 2=hh_hi 3=hh_lo
// fragslot = (t*8 + s)*64 + lane ; element j: W[k = s*32 + (lane>>4)*8 + j][n = t*16 + (lane&15)]
__device__ __align__(16) __bf16 g_wpack[4][4096][8];

__global__ void pack_w(const float* __restrict__ wih, const float* __restrict__ whh) {
    int tid  = blockIdx.x * 256 + threadIdx.x;   // 0..8191
    int m    = tid >> 12;                        // 0 = ih, 1 = hh
    int r    = tid & 4095;
    int lane = r & 63;
    int s    = (r >> 6) & 7;
    int t    = r >> 9;
    int quad = lane >> 4, lrow = lane & 15;
    const float* W = m ? whh : wih;
    int slot = (t * 8 + s) * 64 + lane;
#pragma unroll
    for (int j = 0; j < 8; ++j) {
        int k = s * 32 + quad * 8 + j;
        int n = t * 16 + lrow;
        float x = W[k * 128 + n];
        __bf16 h = (__bf16)x;
        __bf16 l = (__bf16)(x - (float)h);
        g_wpack[2 * m + 0][slot][j] = h;
        g_wpack[2 * m + 1][slot][j] = l;
    }
}

__device__ __forceinline__ float sigmoid_fast(float x) {
    return __builtin_amdgcn_rcpf(1.0f + __expf(-x));
}

__global__ __launch_bounds__(256, 2) void lstm_fused(
        const float* __restrict__ input_,
        const float* __restrict__ hidden,
        const float* __restrict__ bias_ih,
        const float* __restrict__ bias_hh,
        float* __restrict__ out) {
    // per-wave 32x128 cell tile; pitch 132 words -> quad rows 2-way bank alias (free)
    __shared__ __align__(16) float cell[4][32][132];

    const int wave = threadIdx.x >> 6;
    const int lane = threadIdx.x & 63;
    const int quad = lane >> 4;
    const int lrow = lane & 15;
    const long rowBase = (long)blockIdx.x * 128 + wave * 32;

    float bih[8], bhh[8];
#pragma unroll
    for (int t = 0; t < 8; ++t) {
        bih[t] = bias_ih[t * 16 + lrow];
        bhh[t] = bias_hh[t * 16 + lrow];
    }

    floatx4 acc[2][8];
#pragma unroll
    for (int mt = 0; mt < 2; ++mt)
#pragma unroll
        for (int t = 0; t < 8; ++t)
#pragma unroll
            for (int r = 0; r < 4; ++r)
                acc[mt][t][r] = 0.0f;

    // hidden A-fragments kept for GEMM2 (saves a 256MB re-read)
    bf16x8 hh_hi[2][4], hh_lo[2][4];

    // ---------------- GEMM1: [input | hidden] @ Wih ----------------
#pragma unroll
    for (int s = 0; s < 8; ++s) {
        bf16x8 a_hi[2], a_lo[2];
#pragma unroll
        for (int mt = 0; mt < 2; ++mt) {
            const float* src = (s < 4) ? input_ : hidden;
            const float* p = src + (rowBase + mt * 16 + lrow) * 128 + (s & 3) * 32 + quad * 8;
            floatx4 f0 = *(const floatx4*)p;
            floatx4 f1 = *(const floatx4*)(p + 4);
#pragma unroll
            for (int j = 0; j < 4; ++j) {
                __bf16 h0 = (__bf16)f0[j];
                a_hi[mt][j] = h0;
                a_lo[mt][j] = (__bf16)(f0[j] - (float)h0);
                __bf16 h1 = (__bf16)f1[j];
                a_hi[mt][4 + j] = h1;
                a_lo[mt][4 + j] = (__bf16)(f1[j] - (float)h1);
            }
            if (s >= 4) { hh_hi[mt][s - 4] = a_hi[mt]; hh_lo[mt][s - 4] = a_lo[mt]; }
        }
#pragma unroll
        for (int t = 0; t < 8; ++t) {
            bf16x8 bh = *(const bf16x8*)&g_wpack[0][(t * 8 + s) * 64 + lane][0];
            bf16x8 bl = *(const bf16x8*)&g_wpack[1][(t * 8 + s) * 64 + lane][0];
#pragma unroll
            for (int mt = 0; mt < 2; ++mt) {
                acc[mt][t] = __builtin_amdgcn_mfma_f32_16x16x32_bf16(a_hi[mt], bh, acc[mt][t], 0, 0, 0);
                acc[mt][t] = __builtin_amdgcn_mfma_f32_16x16x32_bf16(a_lo[mt], bh, acc[mt][t], 0, 0, 0);
                acc[mt][t] = __builtin_amdgcn_mfma_f32_16x16x32_bf16(a_hi[mt], bl, acc[mt][t], 0, 0, 0);
            }
        }
    }

    // ---- epilogue 1: bias + sigmoid -> cell (LDS), reset acc ----
#pragma unroll
    for (int mt = 0; mt < 2; ++mt)
#pragma unroll
        for (int t = 0; t < 8; ++t)
#pragma unroll
            for (int r = 0; r < 4; ++r) {
                float x = acc[mt][t][r] + bih[t];
                cell[wave][mt * 16 + quad * 4 + r][t * 16 + lrow] = sigmoid_fast(x);
                acc[mt][t][r] = 0.0f;
            }
    __syncthreads();

    // ---------------- GEMM2: [cell | hidden] @ Whh ----------------
#pragma unroll
    for (int s = 0; s < 8; ++s) {
        bf16x8 a_hi[2], a_lo[2];
#pragma unroll
        for (int mt = 0; mt < 2; ++mt) {
            if (s < 4) {
                const float* p = &cell[wave][mt * 16 + lrow][s * 32 + quad * 8];
                floatx4 f0 = *(const floatx4*)p;
                floatx4 f1 = *(const floatx4*)(p + 4);
#pragma unroll
                for (int j = 0; j < 4; ++j) {
                    __bf16 h0 = (__bf16)f0[j];
                    a_hi[mt][j] = h0;
                    a_lo[mt][j] = (__bf16)(f0[j] - (float)h0);
                    __bf16 h1 = (__bf16)f1[j];
                    a_hi[mt][4 + j] = h1;
                    a_lo[mt][4 + j] = (__bf16)(f1[j] - (float)h1);
                }
            } else {
                a_hi[mt] = hh_hi[mt][s - 4];
                a_lo[mt] = hh_lo[mt][s - 4];
            }
        }
#pragma unroll
        for (int t = 0; t < 8; ++t) {
            bf16x8 bh = *(const bf16x8*)&g_wpack[2][(t * 8 + s) * 64 + lane][0];
            bf16x8 bl = *(const bf16x8*)&g_wpack[3][(t * 8 + s) * 64 + lane][0];
#pragma unroll
            for (int mt = 0; mt < 2; ++mt) {
                acc[mt][t] = __builtin_amdgcn_mfma_f32_16x16x32_bf16(a_hi[mt], bh, acc[mt][t], 0, 0, 0);
                acc[mt][t] = __builtin_amdgcn_mfma_f32_16x16x32_bf16(a_lo[mt], bh, acc[mt][t], 0, 0, 0);
                acc[mt][t] = __builtin_amdgcn_mfma_f32_16x16x32_bf16(a_hi[mt], bl, acc[mt][t], 0, 0, 0);
            }
        }
    }

    // ---- epilogue 2: bias + sigmoid -> out ----
#pragma unroll
    for (int mt = 0; mt < 2; ++mt)
#pragma unroll
        for (int t = 0; t < 8; ++t)
#pragma unroll
            for (int r = 0; r < 4; ++r) {
                float x = acc[mt][t][r] + bhh[t];
                out[(rowBase + mt * 16 + quad * 4 + r) * 128 + t * 16 + lrow] = sigmoid_fast(x);
            }
}

extern "C" void kernel_launch(void* const* d_in, const int* in_sizes, int n_in,
                              void* d_out, int out_size, void* d_ws, size_t ws_size,
                              hipStream_t stream) {
    const float* input_ = (const float*)d_in[0];
    const float* hidden = (const float*)d_in[1];
    const float* wih    = (const float*)d_in[2];
    const float* whh    = (const float*)d_in[3];
    const float* bih    = (const float*)d_in[4];
    const float* bhh    = (const float*)d_in[5];
    float* out = (float*)d_out;

    pack_w<<<32, 256, 0, stream>>>(wih, whh);
    lstm_fused<<<4096, 256, 0, stream>>>(input_, hidden, bih, bhh, out);
}